// Round 8
// baseline (445.567 us; speedup 1.0000x reference)
//
#include <hip/hip_runtime.h>
#include <hip/hip_bf16.h>

// Problem constants (from reference)
#define N0 409600
#define N1 40960
#define N2 4096
#define E1c 409600
#define E2c 40960
#define F_IN 512
#define F_HID 256
#define F_OUT 128

using bf16x8 = __attribute__((ext_vector_type(8))) short;
using f32x4  = __attribute__((ext_vector_type(4))) float;

__device__ __forceinline__ ushort f2bf(float f) {
    union { float f; unsigned u; } v; v.f = f;
    unsigned r = v.u + 0x7fffu + ((v.u >> 16) & 1u);
    return (ushort)(r >> 16);
}
__device__ __forceinline__ float bf2f(ushort b) {
    union { unsigned u; float f; } v; v.u = ((unsigned)b) << 16;
    return v.f;
}

// load 8 contiguous elements as bf16x8 (identity for bf16, convert for f32)
__device__ __forceinline__ bf16x8 load8(const ushort* p) {
    return *(const bf16x8*)p;
}
__device__ __forceinline__ bf16x8 load8(const float* p) {
    float4 a = *(const float4*)p;
    float4 b = *(const float4*)(p + 4);
    bf16x8 r;
    r[0] = (short)f2bf(a.x); r[1] = (short)f2bf(a.y);
    r[2] = (short)f2bf(a.z); r[3] = (short)f2bf(a.w);
    r[4] = (short)f2bf(b.x); r[5] = (short)f2bf(b.y);
    r[6] = (short)f2bf(b.z); r[7] = (short)f2bf(b.w);
    return r;
}

// ---------------- x (f32) -> x1b (bf16), all N0 rows, grid-stride ----------------
__global__ void k_cvt(const float* __restrict__ in, ushort* __restrict__ out, long n8) {
    long i = (long)blockIdx.x * blockDim.x + threadIdx.x;
    long stride = (long)gridDim.x * blockDim.x;
    for (; i < n8; i += stride) {
        float4 a = ((const float4*)in)[2 * i];
        float4 b = ((const float4*)in)[2 * i + 1];
        bf16x8 o;
        o[0] = (short)f2bf(a.x); o[1] = (short)f2bf(a.y);
        o[2] = (short)f2bf(a.z); o[3] = (short)f2bf(a.w);
        o[4] = (short)f2bf(b.x); o[5] = (short)f2bf(b.y);
        o[6] = (short)f2bf(b.z); o[7] = (short)f2bf(b.w);
        ((bf16x8*)out)[i] = o;
    }
}

// ---------------- fused: histogram (both layers) + weight transpose/convert ----------------
__global__ void k_prep(const int* __restrict__ dst1, int* __restrict__ cnt1,
                       const int* __restrict__ dst2, int* __restrict__ cnt2,
                       const float* __restrict__ W1l, const float* __restrict__ W1r,
                       const float* __restrict__ W2l, const float* __restrict__ W2r,
                       ushort* __restrict__ W1lT, ushort* __restrict__ W1rT,
                       ushort* __restrict__ W2lT, ushort* __restrict__ W2rT) {
    int idx = blockIdx.x * blockDim.x + threadIdx.x;
    if (idx < E1c) atomicAdd(&cnt1[dst1[idx]], 1);
    else if (idx - E1c < E2c) atomicAdd(&cnt2[dst2[idx - E1c]], 1);
    const int S1 = F_IN * F_HID;
    const int S2 = F_HID * F_OUT;
    if (idx < S1) {
        int k = idx / F_HID, n = idx % F_HID;
        W1lT[(size_t)n * F_IN + k] = f2bf(W1l[idx]);
    } else if (idx < 2 * S1) {
        int j = idx - S1;
        int k = j / F_HID, n = j % F_HID;
        W1rT[(size_t)n * F_IN + k] = f2bf(W1r[j]);
    } else if (idx < 2 * S1 + S2) {
        int j = idx - 2 * S1;
        int k = j / F_OUT, n = j % F_OUT;
        W2lT[(size_t)n * F_HID + k] = f2bf(W2l[j]);
    } else if (idx < 2 * S1 + 2 * S2) {
        int j = idx - 2 * S1 - S2;
        int k = j / F_OUT, n = j % F_OUT;
        W2rT[(size_t)n * F_HID + k] = f2bf(W2r[j]);
    }
}

#define NBLK1 (N1 / 1024)   // 40
#define NBLK2 (N2 / 1024)   // 4

// ---------------- scan phase A (both layers in one grid) ----------------
__global__ __launch_bounds__(1024) void k_scanA2(const int* __restrict__ cnt1, int* __restrict__ off1,
                                                 int* __restrict__ bsum1,
                                                 const int* __restrict__ cnt2, int* __restrict__ off2,
                                                 int* __restrict__ bsum2) {
    __shared__ int wsum[16];
    int blk = blockIdx.x;
    const int* cnt; int* off; int* bsum; int lb;
    if (blk < NBLK1) { cnt = cnt1; off = off1; bsum = bsum1; lb = blk; }
    else             { cnt = cnt2; off = off2; bsum = bsum2; lb = blk - NBLK1; }
    int t = threadIdx.x, lane = t & 63, w = t >> 6;
    int i = lb * 1024 + t;
    int v = cnt[i];
    int s = v;
#pragma unroll
    for (int d = 1; d < 64; d <<= 1) {
        int u = __shfl_up(s, d, 64);
        if (lane >= d) s += u;
    }
    if (lane == 63) wsum[w] = s;
    __syncthreads();
    int wpre = 0, total = 0;
#pragma unroll
    for (int j = 0; j < 16; j++) {
        int u = wsum[j];
        if (j < w) wpre += u;
        total += u;
    }
    off[i] = wpre + (s - v);
    if (t == 0) bsum[lb] = total;
}

// ---------------- scan phase B ----------------
__global__ __launch_bounds__(1024) void k_scanB2(int* __restrict__ off1, int* __restrict__ cur1,
                                                 const int* __restrict__ bsum1,
                                                 int* __restrict__ off2, int* __restrict__ cur2,
                                                 const int* __restrict__ bsum2) {
    __shared__ int s_pre, s_tot;
    int blk = blockIdx.x;
    int* off; int* cur; const int* bsum; int lb, nblk, n;
    if (blk < NBLK1) { off = off1; cur = cur1; bsum = bsum1; lb = blk;         nblk = NBLK1; n = N1; }
    else             { off = off2; cur = cur2; bsum = bsum2; lb = blk - NBLK1; nblk = NBLK2; n = N2; }
    int t = threadIdx.x;
    if (t < 64) {
        int v = (t < nblk) ? bsum[t] : 0;
        int p = (t < lb) ? v : 0;
        int tt = v;
#pragma unroll
        for (int d = 32; d >= 1; d >>= 1) {
            p  += __shfl_xor(p, d, 64);
            tt += __shfl_xor(tt, d, 64);
        }
        if (t == 0) { s_pre = p; s_tot = tt; }
    }
    __syncthreads();
    int i = lb * 1024 + t;
    int val = off[i] + s_pre;
    off[i] = val;
    cur[i] = val;
    if (lb == 0 && t == 0) off[n] = s_tot;
}

// ---------------- fused scatter (both layers) ----------------
__global__ void k_scatter2(const int* __restrict__ src1, const int* __restrict__ dst1,
                           int* __restrict__ cur1, int* __restrict__ perm1,
                           const int* __restrict__ src2, const int* __restrict__ dst2,
                           int* __restrict__ cur2, int* __restrict__ perm2) {
    int e = blockIdx.x * blockDim.x + threadIdx.x;
    if (e < E1c) {
        int d = dst1[e];
        int pos = atomicAdd(&cur1[d], 1);
        perm1[pos] = src1[e];
    } else {
        int e2 = e - E1c;
        if (e2 < E2c) {
            int d = dst2[e2];
            int pos = atomicAdd(&cur2[d], 1);
            perm2[pos] = src2[e2];
        }
    }
}

// ---------------- layer-1 aggregation: bf16 gather -> bf16 mean. 1 wave/row, 16B/lane ----
__global__ __launch_bounds__(64) void k_agg1b(const ushort* __restrict__ x, const int* __restrict__ perm,
                                              const int* __restrict__ off, ushort* __restrict__ mean) {
    int d = blockIdx.x;
    int beg = off[d], end = off[d + 1];
    int t = threadIdx.x;
    float a[8] = {0.f, 0.f, 0.f, 0.f, 0.f, 0.f, 0.f, 0.f};
    int e = beg;
    for (; e + 3 < end; e += 4) {
        bf16x8 v0 = *(const bf16x8*)(x + (size_t)perm[e]     * F_IN + t * 8);
        bf16x8 v1 = *(const bf16x8*)(x + (size_t)perm[e + 1] * F_IN + t * 8);
        bf16x8 v2 = *(const bf16x8*)(x + (size_t)perm[e + 2] * F_IN + t * 8);
        bf16x8 v3 = *(const bf16x8*)(x + (size_t)perm[e + 3] * F_IN + t * 8);
#pragma unroll
        for (int j = 0; j < 8; j++)
            a[j] += (bf2f((ushort)v0[j]) + bf2f((ushort)v1[j]))
                  + (bf2f((ushort)v2[j]) + bf2f((ushort)v3[j]));
    }
    for (; e < end; e++) {
        bf16x8 v0 = *(const bf16x8*)(x + (size_t)perm[e] * F_IN + t * 8);
#pragma unroll
        for (int j = 0; j < 8; j++) a[j] += bf2f((ushort)v0[j]);
    }
    int deg = end - beg;
    float inv = 1.0f / (float)(deg > 0 ? deg : 1);
    bf16x8 o;
#pragma unroll
    for (int j = 0; j < 8; j++) o[j] = (short)f2bf(a[j] * inv);
    *(bf16x8*)(mean + (size_t)d * F_IN + t * 8) = o;
}

// ---------------- layer-2 aggregation: bf16 gather -> bf16 mean. block=64 ----------------
__global__ void k_agg2(const ushort* __restrict__ h, const int* __restrict__ perm,
                       const int* __restrict__ off, ushort* __restrict__ mean) {
    int d = blockIdx.x;
    int beg = off[d], end = off[d + 1];
    int t = threadIdx.x;
    const ushort4* hp = (const ushort4*)h;
    float a0 = 0.f, a1 = 0.f, a2 = 0.f, a3 = 0.f;
    int e = beg;
    for (; e + 3 < end; e += 4) {
        ushort4 v = hp[(size_t)perm[e] * (F_HID / 4) + t];
        ushort4 u = hp[(size_t)perm[e + 1] * (F_HID / 4) + t];
        ushort4 w = hp[(size_t)perm[e + 2] * (F_HID / 4) + t];
        ushort4 z = hp[(size_t)perm[e + 3] * (F_HID / 4) + t];
        a0 += (bf2f(v.x) + bf2f(u.x)) + (bf2f(w.x) + bf2f(z.x));
        a1 += (bf2f(v.y) + bf2f(u.y)) + (bf2f(w.y) + bf2f(z.y));
        a2 += (bf2f(v.z) + bf2f(u.z)) + (bf2f(w.z) + bf2f(z.z));
        a3 += (bf2f(v.w) + bf2f(u.w)) + (bf2f(w.w) + bf2f(z.w));
    }
    for (; e < end; e++) {
        ushort4 v = hp[(size_t)perm[e] * (F_HID / 4) + t];
        a0 += bf2f(v.x); a1 += bf2f(v.y); a2 += bf2f(v.z); a3 += bf2f(v.w);
    }
    int deg = end - beg;
    float inv = 1.0f / (float)(deg > 0 ? deg : 1);
    ushort4 o;
    o.x = f2bf(a0 * inv); o.y = f2bf(a1 * inv);
    o.z = f2bf(a2 * inv); o.w = f2bf(a3 * inv);
    ((ushort4*)mean)[(size_t)d * (F_HID / 4) + t] = o;
}

// ---------------- dual-A bf16 MFMA GEMM ----------------
// C = A1@B1^T + A2@B2^T + bias. A1,A2: MxK. B1T,B2T: NxK bf16 (pre-transposed).
// Waves WM x WN, each wave MF x NF fragments of 16x16. BM = WM*MF*16, BN = WN*NF*16.
#define GBK 32
#define APAD 8
template<int WM, int WN, int MF, int NF, typename TA2>
__global__ __launch_bounds__(256) void k_gemm(
    const ushort* __restrict__ A1, const TA2* __restrict__ A2,
    const ushort* __restrict__ B1T, const ushort* __restrict__ B2T,
    const float* __restrict__ bias, int M, int N, int K, int relu,
    ushort* __restrict__ Cb, float* __restrict__ Cf)
{
    constexpr int BM = WM * MF * 16;
    constexpr int BN = WN * NF * 16;
    static_assert(BM % 64 == 0 && BN % 64 == 0, "tile must be multiple of 64");
    __shared__ ushort As[BM][GBK + APAD];
    __shared__ ushort Bs[BN][GBK + APAD];
    int tid = threadIdx.x;
    int lane = tid & 63;
    int wid = tid >> 6;
    int wm = wid / WN, wn = wid % WN;
    int bm = blockIdx.x * BM, bn = blockIdx.y * BN;

    f32x4 acc[MF][NF];
#pragma unroll
    for (int i = 0; i < MF; i++)
#pragma unroll
        for (int j = 0; j < NF; j++) acc[i][j] = (f32x4){0.f, 0.f, 0.f, 0.f};

    int sr = tid >> 2;
    int sc = (tid & 3) * 8;

    for (int part = 0; part < 2; ++part) {
        const ushort* __restrict__ B = part ? B2T : B1T;
        for (int k0 = 0; k0 < K; k0 += GBK) {
#pragma unroll
            for (int i = 0; i < BM / 64; i++) {
                int r = sr + i * 64;
                bf16x8 av = part
                    ? load8(A2 + (size_t)(bm + r) * K + k0 + sc)
                    : load8(A1 + (size_t)(bm + r) * K + k0 + sc);
                *(bf16x8*)&As[r][sc] = av;
            }
#pragma unroll
            for (int i = 0; i < BN / 64; i++) {
                int r = sr + i * 64;
                *(bf16x8*)&Bs[r][sc] = load8(B + (size_t)(bn + r) * K + k0 + sc);
            }
            __syncthreads();
            bf16x8 af[MF], bfr[NF];
            int r0 = lane & 15;
            int kq = (lane >> 4) * 8;
#pragma unroll
            for (int i = 0; i < MF; i++)
                af[i] = *(const bf16x8*)&As[wm * (MF * 16) + i * 16 + r0][kq];
#pragma unroll
            for (int j = 0; j < NF; j++)
                bfr[j] = *(const bf16x8*)&Bs[wn * (NF * 16) + j * 16 + r0][kq];
#pragma unroll
            for (int i = 0; i < MF; i++)
#pragma unroll
                for (int j = 0; j < NF; j++)
                    acc[i][j] = __builtin_amdgcn_mfma_f32_16x16x32_bf16(af[i], bfr[j], acc[i][j], 0, 0, 0);
            __syncthreads();
        }
    }

    // C/D layout: col = lane&15, row = (lane>>4)*4 + reg
    int cn0 = lane & 15;
    int rq = (lane >> 4) * 4;
#pragma unroll
    for (int i = 0; i < MF; i++) {
#pragma unroll
        for (int j = 0; j < NF; j++) {
            int col = bn + wn * (NF * 16) + j * 16 + cn0;
            float bv = bias[col];
#pragma unroll
            for (int rr = 0; rr < 4; rr++) {
                int row = bm + wm * (MF * 16) + i * 16 + rq + rr;
                float v = acc[i][j][rr] + bv;
                if (relu) v = fmaxf(v, 0.f);
                if (Cb) Cb[(size_t)row * N + col] = f2bf(v);
                if (Cf) Cf[(size_t)row * N + col] = v;
            }
        }
    }
}

static inline size_t align256(size_t x) { return (x + 255) & ~(size_t)255; }

extern "C" void kernel_launch(void* const* d_in, const int* in_sizes, int n_in,
                              void* d_out, int out_size, void* d_ws, size_t ws_size,
                              hipStream_t stream) {
    const float* x = (const float*)d_in[0];
    const int* ei1_src = (const int*)d_in[1];
    const int* ei1_dst = (const int*)d_in[2];
    const int* ei2_src = (const int*)d_in[3];
    const int* ei2_dst = (const int*)d_in[4];
    const float* W1l = (const float*)d_in[5];
    const float* b1 = (const float*)d_in[6];
    const float* W1r = (const float*)d_in[7];
    const float* W2l = (const float*)d_in[8];
    const float* b2 = (const float*)d_in[9];
    const float* W2r = (const float*)d_in[10];
    float* out = (float*)d_out;

    // workspace layout (cnt1+cnt2 contiguous for a single memset)
    char* p = (char*)d_ws;
    size_t o = 0;
    int* cnt1 = (int*)(p + o); o += (size_t)N1 * 4;
    int* cnt2 = (int*)(p + o); o = align256(o + (size_t)N2 * 4);
    int* off1 = (int*)(p + o); o = align256(o + (size_t)(N1 + 1) * 4);
    int* cur1 = (int*)(p + o); o = align256(o + (size_t)N1 * 4);
    int* perm1 = (int*)(p + o); o = align256(o + (size_t)E1c * 4);
    int* off2 = (int*)(p + o); o = align256(o + (size_t)(N2 + 1) * 4);
    int* cur2 = (int*)(p + o); o = align256(o + (size_t)N2 * 4);
    int* perm2 = (int*)(p + o); o = align256(o + (size_t)E2c * 4);
    int* bsum1 = (int*)(p + o); o = align256(o + 64 * 4);
    int* bsum2 = (int*)(p + o); o = align256(o + 64 * 4);
    ushort* x1b   = (ushort*)(p + o); o = align256(o + (size_t)N0 * F_IN * 2);  // all N0 rows
    ushort* mean1 = (ushort*)(p + o); o = align256(o + (size_t)N1 * F_IN * 2);
    ushort* h     = (ushort*)(p + o); o = align256(o + (size_t)N1 * F_HID * 2);
    ushort* mean2 = (ushort*)(p + o); o = align256(o + (size_t)N2 * F_HID * 2);
    ushort* W1lT  = (ushort*)(p + o); o = align256(o + (size_t)F_IN * F_HID * 2);
    ushort* W1rT  = (ushort*)(p + o); o = align256(o + (size_t)F_IN * F_HID * 2);
    ushort* W2lT  = (ushort*)(p + o); o = align256(o + (size_t)F_HID * F_OUT * 2);
    ushort* W2rT  = (ushort*)(p + o); o = align256(o + (size_t)F_HID * F_OUT * 2);

    // zero both histograms with one memset (contiguous)
    hipMemsetAsync(cnt1, 0, (size_t)(N1 + N2) * 4, stream);

    // x -> bf16 (all N0 rows): halves the gather traffic in agg1 and A2 traffic in gemm1
    {
        long n8 = (long)N0 * F_IN / 8;
        k_cvt<<<2048, 256, 0, stream>>>(x, x1b, n8);
    }

    // fused hist + weight transpose
    {
        int total = E1c + E2c;  // >= 2*S1 + 2*S2
        k_prep<<<(total + 255) / 256, 256, 0, stream>>>(
            ei1_dst, cnt1, ei2_dst, cnt2,
            W1l, W1r, W2l, W2r, W1lT, W1rT, W2lT, W2rT);
    }
    k_scanA2<<<NBLK1 + NBLK2, 1024, 0, stream>>>(cnt1, off1, bsum1, cnt2, off2, bsum2);
    k_scanB2<<<NBLK1 + NBLK2, 1024, 0, stream>>>(off1, cur1, bsum1, off2, cur2, bsum2);
    k_scatter2<<<(E1c + E2c + 255) / 256, 256, 0, stream>>>(
        ei1_src, ei1_dst, cur1, perm1, ei2_src, ei2_dst, cur2, perm2);

    // layer 1: aggregate (bf16 gather) + GEMM (64x256 tile: A panels read once)
    k_agg1b<<<N1, 64, 0, stream>>>(x1b, perm1, off1, mean1);
    {
        dim3 grid(N1 / 64, F_HID / 256);   // (640, 1)
        k_gemm<1, 4, 4, 4, ushort><<<grid, 256, 0, stream>>>(mean1, x1b, W1lT, W1rT, b1,
                                                             N1, F_HID, F_IN, 1, h, nullptr);
    }

    // layer 2: aggregate + GEMM (64x64 tile, 128 blocks)
    k_agg2<<<N2, F_HID / 4, 0, stream>>>(h, perm2, off2, mean2);
    {
        dim3 grid(N2 / 64, F_OUT / 64);    // (64, 2)
        k_gemm<2, 2, 2, 2, ushort><<<grid, 256, 0, stream>>>(mean2, h, W2lT, W2rT, b2,
                                                             N2, F_OUT, F_HID, 0, nullptr, out);
    }
}

// Round 9
// 281.229 us; speedup vs baseline: 1.5844x; 1.5844x over previous
//
#include <hip/hip_runtime.h>
#include <hip/hip_bf16.h>

// Problem constants (from reference)
#define N0 409600
#define N1 40960
#define N2 4096
#define E1c 409600
#define E2c 40960
#define F_IN 512
#define F_HID 256
#define F_OUT 128

using bf16x8 = __attribute__((ext_vector_type(8))) short;
using f32x4  = __attribute__((ext_vector_type(4))) float;

__device__ __forceinline__ ushort f2bf(float f) {
    union { float f; unsigned u; } v; v.f = f;
    unsigned r = v.u + 0x7fffu + ((v.u >> 16) & 1u);
    return (ushort)(r >> 16);
}
__device__ __forceinline__ float bf2f(ushort b) {
    union { unsigned u; float f; } v; v.u = ((unsigned)b) << 16;
    return v.f;
}

// load 8 contiguous elements as bf16x8 (identity for bf16, convert for f32)
__device__ __forceinline__ bf16x8 load8(const ushort* p) {
    return *(const bf16x8*)p;
}
__device__ __forceinline__ bf16x8 load8(const float* p) {
    float4 a = *(const float4*)p;
    float4 b = *(const float4*)(p + 4);
    bf16x8 r;
    r[0] = (short)f2bf(a.x); r[1] = (short)f2bf(a.y);
    r[2] = (short)f2bf(a.z); r[3] = (short)f2bf(a.w);
    r[4] = (short)f2bf(b.x); r[5] = (short)f2bf(b.y);
    r[6] = (short)f2bf(b.z); r[7] = (short)f2bf(b.w);
    return r;
}

// ---------------- fused: histogram (both layers) + weight transpose/convert ----------------
__global__ void k_prep(const int* __restrict__ dst1, int* __restrict__ cnt1,
                       const int* __restrict__ dst2, int* __restrict__ cnt2,
                       const float* __restrict__ W1l, const float* __restrict__ W1r,
                       const float* __restrict__ W2l, const float* __restrict__ W2r,
                       ushort* __restrict__ W1lT, ushort* __restrict__ W1rT,
                       ushort* __restrict__ W2lT, ushort* __restrict__ W2rT) {
    int idx = blockIdx.x * blockDim.x + threadIdx.x;
    if (idx < E1c) atomicAdd(&cnt1[dst1[idx]], 1);
    else if (idx - E1c < E2c) atomicAdd(&cnt2[dst2[idx - E1c]], 1);
    const int S1 = F_IN * F_HID;
    const int S2 = F_HID * F_OUT;
    if (idx < S1) {
        int k = idx / F_HID, n = idx % F_HID;
        W1lT[(size_t)n * F_IN + k] = f2bf(W1l[idx]);
    } else if (idx < 2 * S1) {
        int j = idx - S1;
        int k = j / F_HID, n = j % F_HID;
        W1rT[(size_t)n * F_IN + k] = f2bf(W1r[j]);
    } else if (idx < 2 * S1 + S2) {
        int j = idx - 2 * S1;
        int k = j / F_OUT, n = j % F_OUT;
        W2lT[(size_t)n * F_HID + k] = f2bf(W2l[j]);
    } else if (idx < 2 * S1 + 2 * S2) {
        int j = idx - 2 * S1 - S2;
        int k = j / F_OUT, n = j % F_OUT;
        W2rT[(size_t)n * F_HID + k] = f2bf(W2r[j]);
    }
}

#define NBLK1 (N1 / 1024)   // 40
#define NBLK2 (N2 / 1024)   // 4

// ---------------- scan phase A (both layers in one grid) ----------------
__global__ __launch_bounds__(1024) void k_scanA2(const int* __restrict__ cnt1, int* __restrict__ off1,
                                                 int* __restrict__ bsum1,
                                                 const int* __restrict__ cnt2, int* __restrict__ off2,
                                                 int* __restrict__ bsum2) {
    __shared__ int wsum[16];
    int blk = blockIdx.x;
    const int* cnt; int* off; int* bsum; int lb;
    if (blk < NBLK1) { cnt = cnt1; off = off1; bsum = bsum1; lb = blk; }
    else             { cnt = cnt2; off = off2; bsum = bsum2; lb = blk - NBLK1; }
    int t = threadIdx.x, lane = t & 63, w = t >> 6;
    int i = lb * 1024 + t;
    int v = cnt[i];
    int s = v;
#pragma unroll
    for (int d = 1; d < 64; d <<= 1) {
        int u = __shfl_up(s, d, 64);
        if (lane >= d) s += u;
    }
    if (lane == 63) wsum[w] = s;
    __syncthreads();
    int wpre = 0, total = 0;
#pragma unroll
    for (int j = 0; j < 16; j++) {
        int u = wsum[j];
        if (j < w) wpre += u;
        total += u;
    }
    off[i] = wpre + (s - v);
    if (t == 0) bsum[lb] = total;
}

// ---------------- scan phase B ----------------
__global__ __launch_bounds__(1024) void k_scanB2(int* __restrict__ off1, int* __restrict__ cur1,
                                                 const int* __restrict__ bsum1,
                                                 int* __restrict__ off2, int* __restrict__ cur2,
                                                 const int* __restrict__ bsum2) {
    __shared__ int s_pre, s_tot;
    int blk = blockIdx.x;
    int* off; int* cur; const int* bsum; int lb, nblk, n;
    if (blk < NBLK1) { off = off1; cur = cur1; bsum = bsum1; lb = blk;         nblk = NBLK1; n = N1; }
    else             { off = off2; cur = cur2; bsum = bsum2; lb = blk - NBLK1; nblk = NBLK2; n = N2; }
    int t = threadIdx.x;
    if (t < 64) {
        int v = (t < nblk) ? bsum[t] : 0;
        int p = (t < lb) ? v : 0;
        int tt = v;
#pragma unroll
        for (int d = 32; d >= 1; d >>= 1) {
            p  += __shfl_xor(p, d, 64);
            tt += __shfl_xor(tt, d, 64);
        }
        if (t == 0) { s_pre = p; s_tot = tt; }
    }
    __syncthreads();
    int i = lb * 1024 + t;
    int val = off[i] + s_pre;
    off[i] = val;
    cur[i] = val;
    if (lb == 0 && t == 0) off[n] = s_tot;
}

// ---------------- fused scatter (both layers) ----------------
__global__ void k_scatter2(const int* __restrict__ src1, const int* __restrict__ dst1,
                           int* __restrict__ cur1, int* __restrict__ perm1,
                           const int* __restrict__ src2, const int* __restrict__ dst2,
                           int* __restrict__ cur2, int* __restrict__ perm2) {
    int e = blockIdx.x * blockDim.x + threadIdx.x;
    if (e < E1c) {
        int d = dst1[e];
        int pos = atomicAdd(&cur1[d], 1);
        perm1[pos] = src1[e];
    } else {
        int e2 = e - E1c;
        if (e2 < E2c) {
            int d = dst2[e2];
            int pos = atomicAdd(&cur2[d], 1);
            perm2[pos] = src2[e2];
        }
    }
}

// ---------------- layer-1 aggregation: f32 gather -> bf16 mean. block=128 ----------------
__global__ void k_agg1(const float* __restrict__ x, const int* __restrict__ perm,
                       const int* __restrict__ off, ushort* __restrict__ mean) {
    int d = blockIdx.x;
    int beg = off[d], end = off[d + 1];
    int t = threadIdx.x;
    const float4* xp = (const float4*)x;
    float ax = 0.f, ay = 0.f, az = 0.f, aw = 0.f;
    int e = beg;
    for (; e + 3 < end; e += 4) {
        int s0 = perm[e], s1 = perm[e + 1], s2 = perm[e + 2], s3 = perm[e + 3];
        float4 v0 = xp[(size_t)s0 * (F_IN / 4) + t];
        float4 v1 = xp[(size_t)s1 * (F_IN / 4) + t];
        float4 v2 = xp[(size_t)s2 * (F_IN / 4) + t];
        float4 v3 = xp[(size_t)s3 * (F_IN / 4) + t];
        ax += (v0.x + v1.x) + (v2.x + v3.x);
        ay += (v0.y + v1.y) + (v2.y + v3.y);
        az += (v0.z + v1.z) + (v2.z + v3.z);
        aw += (v0.w + v1.w) + (v2.w + v3.w);
    }
    for (; e < end; e++) {
        float4 v0 = xp[(size_t)perm[e] * (F_IN / 4) + t];
        ax += v0.x; ay += v0.y; az += v0.z; aw += v0.w;
    }
    int deg = end - beg;
    float inv = 1.0f / (float)(deg > 0 ? deg : 1);
    ushort4 o;
    o.x = f2bf(ax * inv); o.y = f2bf(ay * inv);
    o.z = f2bf(az * inv); o.w = f2bf(aw * inv);
    ((ushort4*)mean)[(size_t)d * (F_IN / 4) + t] = o;
}

// ---------------- layer-2 aggregation: bf16 gather -> bf16 mean. block=64 ----------------
__global__ void k_agg2(const ushort* __restrict__ h, const int* __restrict__ perm,
                       const int* __restrict__ off, ushort* __restrict__ mean) {
    int d = blockIdx.x;
    int beg = off[d], end = off[d + 1];
    int t = threadIdx.x;
    const ushort4* hp = (const ushort4*)h;
    float a0 = 0.f, a1 = 0.f, a2 = 0.f, a3 = 0.f;
    int e = beg;
    for (; e + 3 < end; e += 4) {
        ushort4 v = hp[(size_t)perm[e] * (F_HID / 4) + t];
        ushort4 u = hp[(size_t)perm[e + 1] * (F_HID / 4) + t];
        ushort4 w = hp[(size_t)perm[e + 2] * (F_HID / 4) + t];
        ushort4 z = hp[(size_t)perm[e + 3] * (F_HID / 4) + t];
        a0 += (bf2f(v.x) + bf2f(u.x)) + (bf2f(w.x) + bf2f(z.x));
        a1 += (bf2f(v.y) + bf2f(u.y)) + (bf2f(w.y) + bf2f(z.y));
        a2 += (bf2f(v.z) + bf2f(u.z)) + (bf2f(w.z) + bf2f(z.z));
        a3 += (bf2f(v.w) + bf2f(u.w)) + (bf2f(w.w) + bf2f(z.w));
    }
    for (; e < end; e++) {
        ushort4 v = hp[(size_t)perm[e] * (F_HID / 4) + t];
        a0 += bf2f(v.x); a1 += bf2f(v.y); a2 += bf2f(v.z); a3 += bf2f(v.w);
    }
    int deg = end - beg;
    float inv = 1.0f / (float)(deg > 0 ? deg : 1);
    ushort4 o;
    o.x = f2bf(a0 * inv); o.y = f2bf(a1 * inv);
    o.z = f2bf(a2 * inv); o.w = f2bf(a3 * inv);
    ((ushort4*)mean)[(size_t)d * (F_HID / 4) + t] = o;
}

// ---------------- dual-A bf16 MFMA GEMM ----------------
// C = A1@B1^T + A2@B2^T + bias. A1: MxK bf16. A2: MxK (bf16 or f32, converted on stage).
// B1T,B2T: NxK bf16 (pre-transposed). Waves WM x WN, each wave MF x NF fragments of 16x16.
// BM = WM*MF*16, BN = WN*NF*16. MINW = min waves/SIMD for launch_bounds.
#define GBK 32
#define APAD 8
template<int WM, int WN, int MF, int NF, int MINW, typename TA2>
__global__ __launch_bounds__(256, MINW) void k_gemm(
    const ushort* __restrict__ A1, const TA2* __restrict__ A2,
    const ushort* __restrict__ B1T, const ushort* __restrict__ B2T,
    const float* __restrict__ bias, int M, int N, int K, int relu,
    ushort* __restrict__ Cb, float* __restrict__ Cf)
{
    constexpr int BM = WM * MF * 16;
    constexpr int BN = WN * NF * 16;
    static_assert(BM % 64 == 0 && BN % 64 == 0, "tile must be multiple of 64");
    __shared__ ushort As[BM][GBK + APAD];
    __shared__ ushort Bs[BN][GBK + APAD];
    int tid = threadIdx.x;
    int lane = tid & 63;
    int wid = tid >> 6;
    int wm = wid / WN, wn = wid % WN;
    int bm = blockIdx.x * BM, bn = blockIdx.y * BN;

    f32x4 acc[MF][NF];
#pragma unroll
    for (int i = 0; i < MF; i++)
#pragma unroll
        for (int j = 0; j < NF; j++) acc[i][j] = (f32x4){0.f, 0.f, 0.f, 0.f};

    int sr = tid >> 2;
    int sc = (tid & 3) * 8;

    for (int part = 0; part < 2; ++part) {
        const ushort* __restrict__ B = part ? B2T : B1T;
        for (int k0 = 0; k0 < K; k0 += GBK) {
#pragma unroll
            for (int i = 0; i < BM / 64; i++) {
                int r = sr + i * 64;
                bf16x8 av = part
                    ? load8(A2 + (size_t)(bm + r) * K + k0 + sc)
                    : load8(A1 + (size_t)(bm + r) * K + k0 + sc);
                *(bf16x8*)&As[r][sc] = av;
            }
#pragma unroll
            for (int i = 0; i < BN / 64; i++) {
                int r = sr + i * 64;
                *(bf16x8*)&Bs[r][sc] = load8(B + (size_t)(bn + r) * K + k0 + sc);
            }
            __syncthreads();
            bf16x8 af[MF], bfr[NF];
            int r0 = lane & 15;
            int kq = (lane >> 4) * 8;
#pragma unroll
            for (int i = 0; i < MF; i++)
                af[i] = *(const bf16x8*)&As[wm * (MF * 16) + i * 16 + r0][kq];
#pragma unroll
            for (int j = 0; j < NF; j++)
                bfr[j] = *(const bf16x8*)&Bs[wn * (NF * 16) + j * 16 + r0][kq];
#pragma unroll
            for (int i = 0; i < MF; i++)
#pragma unroll
                for (int j = 0; j < NF; j++)
                    acc[i][j] = __builtin_amdgcn_mfma_f32_16x16x32_bf16(af[i], bfr[j], acc[i][j], 0, 0, 0);
            __syncthreads();
        }
    }

    // C/D layout: col = lane&15, row = (lane>>4)*4 + reg
    int cn0 = lane & 15;
    int rq = (lane >> 4) * 4;
#pragma unroll
    for (int i = 0; i < MF; i++) {
#pragma unroll
        for (int j = 0; j < NF; j++) {
            int col = bn + wn * (NF * 16) + j * 16 + cn0;
            float bv = bias[col];
#pragma unroll
            for (int rr = 0; rr < 4; rr++) {
                int row = bm + wm * (MF * 16) + i * 16 + rq + rr;
                float v = acc[i][j][rr] + bv;
                if (relu) v = fmaxf(v, 0.f);
                if (Cb) Cb[(size_t)row * N + col] = f2bf(v);
                if (Cf) Cf[(size_t)row * N + col] = v;
            }
        }
    }
}

static inline size_t align256(size_t x) { return (x + 255) & ~(size_t)255; }

extern "C" void kernel_launch(void* const* d_in, const int* in_sizes, int n_in,
                              void* d_out, int out_size, void* d_ws, size_t ws_size,
                              hipStream_t stream) {
    const float* x = (const float*)d_in[0];
    const int* ei1_src = (const int*)d_in[1];
    const int* ei1_dst = (const int*)d_in[2];
    const int* ei2_src = (const int*)d_in[3];
    const int* ei2_dst = (const int*)d_in[4];
    const float* W1l = (const float*)d_in[5];
    const float* b1 = (const float*)d_in[6];
    const float* W1r = (const float*)d_in[7];
    const float* W2l = (const float*)d_in[8];
    const float* b2 = (const float*)d_in[9];
    const float* W2r = (const float*)d_in[10];
    float* out = (float*)d_out;

    // workspace layout (cnt1+cnt2 contiguous for a single memset)
    char* p = (char*)d_ws;
    size_t o = 0;
    int* cnt1 = (int*)(p + o); o += (size_t)N1 * 4;
    int* cnt2 = (int*)(p + o); o = align256(o + (size_t)N2 * 4);
    int* off1 = (int*)(p + o); o = align256(o + (size_t)(N1 + 1) * 4);
    int* cur1 = (int*)(p + o); o = align256(o + (size_t)N1 * 4);
    int* perm1 = (int*)(p + o); o = align256(o + (size_t)E1c * 4);
    int* off2 = (int*)(p + o); o = align256(o + (size_t)(N2 + 1) * 4);
    int* cur2 = (int*)(p + o); o = align256(o + (size_t)N2 * 4);
    int* perm2 = (int*)(p + o); o = align256(o + (size_t)E2c * 4);
    int* bsum1 = (int*)(p + o); o = align256(o + 64 * 4);
    int* bsum2 = (int*)(p + o); o = align256(o + 64 * 4);
    ushort* mean1 = (ushort*)(p + o); o = align256(o + (size_t)N1 * F_IN * 2);
    ushort* h     = (ushort*)(p + o); o = align256(o + (size_t)N1 * F_HID * 2);
    ushort* mean2 = (ushort*)(p + o); o = align256(o + (size_t)N2 * F_HID * 2);
    ushort* W1lT  = (ushort*)(p + o); o = align256(o + (size_t)F_IN * F_HID * 2);
    ushort* W1rT  = (ushort*)(p + o); o = align256(o + (size_t)F_IN * F_HID * 2);
    ushort* W2lT  = (ushort*)(p + o); o = align256(o + (size_t)F_HID * F_OUT * 2);
    ushort* W2rT  = (ushort*)(p + o); o = align256(o + (size_t)F_HID * F_OUT * 2);

    // zero both histograms with one memset (contiguous)
    hipMemsetAsync(cnt1, 0, (size_t)(N1 + N2) * 4, stream);

    // fused hist + weight transpose
    {
        int total = E1c + E2c;  // >= 2*S1 + 2*S2
        k_prep<<<(total + 255) / 256, 256, 0, stream>>>(
            ei1_dst, cnt1, ei2_dst, cnt2,
            W1l, W1r, W2l, W2r, W1lT, W1rT, W2lT, W2rT);
    }
    k_scanA2<<<NBLK1 + NBLK2, 1024, 0, stream>>>(cnt1, off1, bsum1, cnt2, off2, bsum2);
    k_scanB2<<<NBLK1 + NBLK2, 1024, 0, stream>>>(off1, cur1, bsum1, off2, cur2, bsum2);
    k_scatter2<<<(E1c + E2c + 255) / 256, 256, 0, stream>>>(
        ei1_src, ei1_dst, cur1, perm1, ei2_src, ei2_dst, cur2, perm2);

    // layer 1: aggregate (f32 gather) + GEMM (128x256 tile: A once, 32 MFMA / 12 ds_read per wave-step)
    k_agg1<<<N1, F_IN / 4, 0, stream>>>(x, perm1, off1, mean1);
    {
        dim3 grid(N1 / 128, F_HID / 256);  // (320, 1)
        k_gemm<2, 2, 4, 8, 2, float><<<grid, 256, 0, stream>>>(mean1, x, W1lT, W1rT, b1,
                                                               N1, F_HID, F_IN, 1, h, nullptr);
    }

    // layer 2: aggregate + GEMM (64x64 tile, 128 blocks)
    k_agg2<<<N2, F_HID / 4, 0, stream>>>(h, perm2, off2, mean2);
    {
        dim3 grid(N2 / 64, F_OUT / 64);    // (64, 2)
        k_gemm<2, 2, 2, 2, 4, ushort><<<grid, 256, 0, stream>>>(mean2, h, W2lT, W2rT, b2,
                                                                N2, F_OUT, F_HID, 0, nullptr, out);
    }
}

// Round 10
// 264.317 us; speedup vs baseline: 1.6857x; 1.0640x over previous
//
#include <hip/hip_runtime.h>
#include <hip/hip_bf16.h>

// Problem constants (from reference)
#define N0 409600
#define N1 40960
#define N2 4096
#define E1c 409600
#define E2c 40960
#define F_IN 512
#define F_HID 256
#define F_OUT 128

using bf16x8 = __attribute__((ext_vector_type(8))) short;
using f32x4  = __attribute__((ext_vector_type(4))) float;

__device__ __forceinline__ ushort f2bf(float f) {
    union { float f; unsigned u; } v; v.f = f;
    unsigned r = v.u + 0x7fffu + ((v.u >> 16) & 1u);
    return (ushort)(r >> 16);
}
__device__ __forceinline__ float bf2f(ushort b) {
    union { unsigned u; float f; } v; v.u = ((unsigned)b) << 16;
    return v.f;
}

// load 8 contiguous elements as bf16x8 (identity for bf16, convert for f32)
__device__ __forceinline__ bf16x8 load8(const ushort* p) {
    return *(const bf16x8*)p;
}
__device__ __forceinline__ bf16x8 load8(const float* p) {
    float4 a = *(const float4*)p;
    float4 b = *(const float4*)(p + 4);
    bf16x8 r;
    r[0] = (short)f2bf(a.x); r[1] = (short)f2bf(a.y);
    r[2] = (short)f2bf(a.z); r[3] = (short)f2bf(a.w);
    r[4] = (short)f2bf(b.x); r[5] = (short)f2bf(b.y);
    r[6] = (short)f2bf(b.z); r[7] = (short)f2bf(b.w);
    return r;
}

// ---------------- fused: histogram (both layers) + weight transpose/convert ----------------
__global__ void k_prep(const int* __restrict__ dst1, int* __restrict__ cnt1,
                       const int* __restrict__ dst2, int* __restrict__ cnt2,
                       const float* __restrict__ W1l, const float* __restrict__ W1r,
                       const float* __restrict__ W2l, const float* __restrict__ W2r,
                       ushort* __restrict__ W1lT, ushort* __restrict__ W1rT,
                       ushort* __restrict__ W2lT, ushort* __restrict__ W2rT) {
    int idx = blockIdx.x * blockDim.x + threadIdx.x;
    if (idx < E1c) atomicAdd(&cnt1[dst1[idx]], 1);
    else if (idx - E1c < E2c) atomicAdd(&cnt2[dst2[idx - E1c]], 1);
    const int S1 = F_IN * F_HID;
    const int S2 = F_HID * F_OUT;
    if (idx < S1) {
        int k = idx / F_HID, n = idx % F_HID;
        W1lT[(size_t)n * F_IN + k] = f2bf(W1l[idx]);
    } else if (idx < 2 * S1) {
        int j = idx - S1;
        int k = j / F_HID, n = j % F_HID;
        W1rT[(size_t)n * F_IN + k] = f2bf(W1r[j]);
    } else if (idx < 2 * S1 + S2) {
        int j = idx - 2 * S1;
        int k = j / F_OUT, n = j % F_OUT;
        W2lT[(size_t)n * F_HID + k] = f2bf(W2l[j]);
    } else if (idx < 2 * S1 + 2 * S2) {
        int j = idx - 2 * S1 - S2;
        int k = j / F_OUT, n = j % F_OUT;
        W2rT[(size_t)n * F_HID + k] = f2bf(W2r[j]);
    }
}

#define NBLK1 (N1 / 1024)   // 40
#define NBLK2 (N2 / 1024)   // 4

// ---------------- scan phase A (both layers in one grid) ----------------
__global__ __launch_bounds__(1024) void k_scanA2(const int* __restrict__ cnt1, int* __restrict__ off1,
                                                 int* __restrict__ bsum1,
                                                 const int* __restrict__ cnt2, int* __restrict__ off2,
                                                 int* __restrict__ bsum2) {
    __shared__ int wsum[16];
    int blk = blockIdx.x;
    const int* cnt; int* off; int* bsum; int lb;
    if (blk < NBLK1) { cnt = cnt1; off = off1; bsum = bsum1; lb = blk; }
    else             { cnt = cnt2; off = off2; bsum = bsum2; lb = blk - NBLK1; }
    int t = threadIdx.x, lane = t & 63, w = t >> 6;
    int i = lb * 1024 + t;
    int v = cnt[i];
    int s = v;
#pragma unroll
    for (int d = 1; d < 64; d <<= 1) {
        int u = __shfl_up(s, d, 64);
        if (lane >= d) s += u;
    }
    if (lane == 63) wsum[w] = s;
    __syncthreads();
    int wpre = 0, total = 0;
#pragma unroll
    for (int j = 0; j < 16; j++) {
        int u = wsum[j];
        if (j < w) wpre += u;
        total += u;
    }
    off[i] = wpre + (s - v);
    if (t == 0) bsum[lb] = total;
}

// ---------------- scan phase B ----------------
__global__ __launch_bounds__(1024) void k_scanB2(int* __restrict__ off1, int* __restrict__ cur1,
                                                 const int* __restrict__ bsum1,
                                                 int* __restrict__ off2, int* __restrict__ cur2,
                                                 const int* __restrict__ bsum2) {
    __shared__ int s_pre, s_tot;
    int blk = blockIdx.x;
    int* off; int* cur; const int* bsum; int lb, nblk, n;
    if (blk < NBLK1) { off = off1; cur = cur1; bsum = bsum1; lb = blk;         nblk = NBLK1; n = N1; }
    else             { off = off2; cur = cur2; bsum = bsum2; lb = blk - NBLK1; nblk = NBLK2; n = N2; }
    int t = threadIdx.x;
    if (t < 64) {
        int v = (t < nblk) ? bsum[t] : 0;
        int p = (t < lb) ? v : 0;
        int tt = v;
#pragma unroll
        for (int d = 32; d >= 1; d >>= 1) {
            p  += __shfl_xor(p, d, 64);
            tt += __shfl_xor(tt, d, 64);
        }
        if (t == 0) { s_pre = p; s_tot = tt; }
    }
    __syncthreads();
    int i = lb * 1024 + t;
    int val = off[i] + s_pre;
    off[i] = val;
    cur[i] = val;
    if (lb == 0 && t == 0) off[n] = s_tot;
}

// ---------------- fused scatter (both layers) ----------------
__global__ void k_scatter2(const int* __restrict__ src1, const int* __restrict__ dst1,
                           int* __restrict__ cur1, int* __restrict__ perm1,
                           const int* __restrict__ src2, const int* __restrict__ dst2,
                           int* __restrict__ cur2, int* __restrict__ perm2) {
    int e = blockIdx.x * blockDim.x + threadIdx.x;
    if (e < E1c) {
        int d = dst1[e];
        int pos = atomicAdd(&cur1[d], 1);
        perm1[pos] = src1[e];
    } else {
        int e2 = e - E1c;
        if (e2 < E2c) {
            int d = dst2[e2];
            int pos = atomicAdd(&cur2[d], 1);
            perm2[pos] = src2[e2];
        }
    }
}

// ---------------- layer-1 aggregation: f32 gather -> bf16 mean. block=128 ----------------
__global__ void k_agg1(const float* __restrict__ x, const int* __restrict__ perm,
                       const int* __restrict__ off, ushort* __restrict__ mean) {
    int d = blockIdx.x;
    int beg = off[d], end = off[d + 1];
    int t = threadIdx.x;
    const float4* xp = (const float4*)x;
    float ax = 0.f, ay = 0.f, az = 0.f, aw = 0.f;
    int e = beg;
    for (; e + 3 < end; e += 4) {
        int s0 = perm[e], s1 = perm[e + 1], s2 = perm[e + 2], s3 = perm[e + 3];
        float4 v0 = xp[(size_t)s0 * (F_IN / 4) + t];
        float4 v1 = xp[(size_t)s1 * (F_IN / 4) + t];
        float4 v2 = xp[(size_t)s2 * (F_IN / 4) + t];
        float4 v3 = xp[(size_t)s3 * (F_IN / 4) + t];
        ax += (v0.x + v1.x) + (v2.x + v3.x);
        ay += (v0.y + v1.y) + (v2.y + v3.y);
        az += (v0.z + v1.z) + (v2.z + v3.z);
        aw += (v0.w + v1.w) + (v2.w + v3.w);
    }
    for (; e < end; e++) {
        float4 v0 = xp[(size_t)perm[e] * (F_IN / 4) + t];
        ax += v0.x; ay += v0.y; az += v0.z; aw += v0.w;
    }
    int deg = end - beg;
    float inv = 1.0f / (float)(deg > 0 ? deg : 1);
    ushort4 o;
    o.x = f2bf(ax * inv); o.y = f2bf(ay * inv);
    o.z = f2bf(az * inv); o.w = f2bf(aw * inv);
    ((ushort4*)mean)[(size_t)d * (F_IN / 4) + t] = o;
}

// ---------------- layer-2 aggregation: bf16 gather -> bf16 mean. block=64 ----------------
__global__ void k_agg2(const ushort* __restrict__ h, const int* __restrict__ perm,
                       const int* __restrict__ off, ushort* __restrict__ mean) {
    int d = blockIdx.x;
    int beg = off[d], end = off[d + 1];
    int t = threadIdx.x;
    const ushort4* hp = (const ushort4*)h;
    float a0 = 0.f, a1 = 0.f, a2 = 0.f, a3 = 0.f;
    int e = beg;
    for (; e + 3 < end; e += 4) {
        ushort4 v = hp[(size_t)perm[e] * (F_HID / 4) + t];
        ushort4 u = hp[(size_t)perm[e + 1] * (F_HID / 4) + t];
        ushort4 w = hp[(size_t)perm[e + 2] * (F_HID / 4) + t];
        ushort4 z = hp[(size_t)perm[e + 3] * (F_HID / 4) + t];
        a0 += (bf2f(v.x) + bf2f(u.x)) + (bf2f(w.x) + bf2f(z.x));
        a1 += (bf2f(v.y) + bf2f(u.y)) + (bf2f(w.y) + bf2f(z.y));
        a2 += (bf2f(v.z) + bf2f(u.z)) + (bf2f(w.z) + bf2f(z.z));
        a3 += (bf2f(v.w) + bf2f(u.w)) + (bf2f(w.w) + bf2f(z.w));
    }
    for (; e < end; e++) {
        ushort4 v = hp[(size_t)perm[e] * (F_HID / 4) + t];
        a0 += bf2f(v.x); a1 += bf2f(v.y); a2 += bf2f(v.z); a3 += bf2f(v.w);
    }
    int deg = end - beg;
    float inv = 1.0f / (float)(deg > 0 ? deg : 1);
    ushort4 o;
    o.x = f2bf(a0 * inv); o.y = f2bf(a1 * inv);
    o.z = f2bf(a2 * inv); o.w = f2bf(a3 * inv);
    ((ushort4*)mean)[(size_t)d * (F_HID / 4) + t] = o;
}

// ---------------- dual-A bf16 MFMA GEMM, 2-phase pipelined ----------------
// C = A1@B1^T + A2@B2^T + bias. A1: MxK bf16. A2: MxK (bf16 or f32, converted on stage).
// B1T,B2T: NxK bf16 (pre-transposed). Waves WM x WN, each MF x NF 16x16 frags.
// Flattened 2*(K/32) step pipeline, double-buffered LDS, ONE barrier per step:
//   { ds_write regs->LDS[buf]; barrier; issue global loads for s+1; ds_read + MFMA }
#define GBK 32
#define APAD 8
template<int WM, int WN, int MF, int NF, int K, int MINW, typename TA2>
__global__ __launch_bounds__(256, MINW) void k_gemm(
    const ushort* __restrict__ A1, const TA2* __restrict__ A2,
    const ushort* __restrict__ B1T, const ushort* __restrict__ B2T,
    const float* __restrict__ bias, int M, int N, int relu,
    ushort* __restrict__ Cb, float* __restrict__ Cf)
{
    constexpr int BM = WM * MF * 16;
    constexpr int BN = WN * NF * 16;
    constexpr int KS = K / GBK;       // steps per part
    constexpr int NS = 2 * KS;        // total pipeline steps
    static_assert(BM % 64 == 0 && BN % 64 == 0, "tile must be multiple of 64");
    __shared__ ushort As[2][BM][GBK + APAD];
    __shared__ ushort Bs[2][BN][GBK + APAD];
    int tid = threadIdx.x;
    int lane = tid & 63;
    int wid = tid >> 6;
    int wm = wid / WN, wn = wid % WN;
    int bm = blockIdx.x * BM, bn = blockIdx.y * BN;

    f32x4 acc[MF][NF];
#pragma unroll
    for (int i = 0; i < MF; i++)
#pragma unroll
        for (int j = 0; j < NF; j++) acc[i][j] = (f32x4){0.f, 0.f, 0.f, 0.f};

    int sr = tid >> 2;        // 0..63
    int sc = (tid & 3) * 8;   // 0,8,16,24
    int r0 = lane & 15, kq = (lane >> 4) * 8;

    bf16x8 ra[BM / 64], rb[BN / 64];
    // prologue: step 0 (part 0, k0 = 0)
#pragma unroll
    for (int i = 0; i < BM / 64; i++)
        ra[i] = load8(A1 + (size_t)(bm + sr + i * 64) * K + sc);
#pragma unroll
    for (int i = 0; i < BN / 64; i++)
        rb[i] = load8(B1T + (size_t)(bn + sr + i * 64) * K + sc);

    for (int s = 0; s < NS; ++s) {
        int buf = s & 1;
        // write staged regs to LDS
#pragma unroll
        for (int i = 0; i < BM / 64; i++) *(bf16x8*)&As[buf][sr + i * 64][sc] = ra[i];
#pragma unroll
        for (int i = 0; i < BN / 64; i++) *(bf16x8*)&Bs[buf][sr + i * 64][sc] = rb[i];
        __syncthreads();
        // issue next step's global loads (latency hides under MFMA below)
        if (s + 1 < NS) {
            int s1 = s + 1;
            int part1 = (s1 >= KS) ? 1 : 0;
            int k01 = (s1 - part1 * KS) * GBK;
#pragma unroll
            for (int i = 0; i < BM / 64; i++) {
                size_t idx = (size_t)(bm + sr + i * 64) * K + k01 + sc;
                ra[i] = part1 ? load8(A2 + idx) : load8(A1 + idx);
            }
            const ushort* __restrict__ B = part1 ? B2T : B1T;
#pragma unroll
            for (int i = 0; i < BN / 64; i++)
                rb[i] = load8(B + (size_t)(bn + sr + i * 64) * K + k01 + sc);
        }
        // compute current step from LDS
        bf16x8 af[MF], bfr[NF];
#pragma unroll
        for (int i = 0; i < MF; i++)
            af[i] = *(const bf16x8*)&As[buf][wm * (MF * 16) + i * 16 + r0][kq];
#pragma unroll
        for (int j = 0; j < NF; j++)
            bfr[j] = *(const bf16x8*)&Bs[buf][wn * (NF * 16) + j * 16 + r0][kq];
#pragma unroll
        for (int i = 0; i < MF; i++)
#pragma unroll
            for (int j = 0; j < NF; j++)
                acc[i][j] = __builtin_amdgcn_mfma_f32_16x16x32_bf16(af[i], bfr[j], acc[i][j], 0, 0, 0);
        // no second barrier: next step writes the other LDS buffer
    }

    // C/D layout: col = lane&15, row = (lane>>4)*4 + reg
    int cn0 = lane & 15;
    int rq = (lane >> 4) * 4;
#pragma unroll
    for (int i = 0; i < MF; i++) {
#pragma unroll
        for (int j = 0; j < NF; j++) {
            int col = bn + wn * (NF * 16) + j * 16 + cn0;
            float bv = bias[col];
#pragma unroll
            for (int rr = 0; rr < 4; rr++) {
                int row = bm + wm * (MF * 16) + i * 16 + rq + rr;
                float v = acc[i][j][rr] + bv;
                if (relu) v = fmaxf(v, 0.f);
                if (Cb) Cb[(size_t)row * N + col] = f2bf(v);
                if (Cf) Cf[(size_t)row * N + col] = v;
            }
        }
    }
}

static inline size_t align256(size_t x) { return (x + 255) & ~(size_t)255; }

extern "C" void kernel_launch(void* const* d_in, const int* in_sizes, int n_in,
                              void* d_out, int out_size, void* d_ws, size_t ws_size,
                              hipStream_t stream) {
    const float* x = (const float*)d_in[0];
    const int* ei1_src = (const int*)d_in[1];
    const int* ei1_dst = (const int*)d_in[2];
    const int* ei2_src = (const int*)d_in[3];
    const int* ei2_dst = (const int*)d_in[4];
    const float* W1l = (const float*)d_in[5];
    const float* b1 = (const float*)d_in[6];
    const float* W1r = (const float*)d_in[7];
    const float* W2l = (const float*)d_in[8];
    const float* b2 = (const float*)d_in[9];
    const float* W2r = (const float*)d_in[10];
    float* out = (float*)d_out;

    // workspace layout (cnt1+cnt2 contiguous for a single memset)
    char* p = (char*)d_ws;
    size_t o = 0;
    int* cnt1 = (int*)(p + o); o += (size_t)N1 * 4;
    int* cnt2 = (int*)(p + o); o = align256(o + (size_t)N2 * 4);
    int* off1 = (int*)(p + o); o = align256(o + (size_t)(N1 + 1) * 4);
    int* cur1 = (int*)(p + o); o = align256(o + (size_t)N1 * 4);
    int* perm1 = (int*)(p + o); o = align256(o + (size_t)E1c * 4);
    int* off2 = (int*)(p + o); o = align256(o + (size_t)(N2 + 1) * 4);
    int* cur2 = (int*)(p + o); o = align256(o + (size_t)N2 * 4);
    int* perm2 = (int*)(p + o); o = align256(o + (size_t)E2c * 4);
    int* bsum1 = (int*)(p + o); o = align256(o + 64 * 4);
    int* bsum2 = (int*)(p + o); o = align256(o + 64 * 4);
    ushort* mean1 = (ushort*)(p + o); o = align256(o + (size_t)N1 * F_IN * 2);
    ushort* h     = (ushort*)(p + o); o = align256(o + (size_t)N1 * F_HID * 2);
    ushort* mean2 = (ushort*)(p + o); o = align256(o + (size_t)N2 * F_HID * 2);
    ushort* W1lT  = (ushort*)(p + o); o = align256(o + (size_t)F_IN * F_HID * 2);
    ushort* W1rT  = (ushort*)(p + o); o = align256(o + (size_t)F_IN * F_HID * 2);
    ushort* W2lT  = (ushort*)(p + o); o = align256(o + (size_t)F_HID * F_OUT * 2);
    ushort* W2rT  = (ushort*)(p + o); o = align256(o + (size_t)F_HID * F_OUT * 2);

    // zero both histograms with one memset (contiguous)
    hipMemsetAsync(cnt1, 0, (size_t)(N1 + N2) * 4, stream);

    // fused hist + weight transpose
    {
        int total = E1c + E2c;  // >= 2*S1 + 2*S2
        k_prep<<<(total + 255) / 256, 256, 0, stream>>>(
            ei1_dst, cnt1, ei2_dst, cnt2,
            W1l, W1r, W2l, W2r, W1lT, W1rT, W2lT, W2rT);
    }
    k_scanA2<<<NBLK1 + NBLK2, 1024, 0, stream>>>(cnt1, off1, bsum1, cnt2, off2, bsum2);
    k_scanB2<<<NBLK1 + NBLK2, 1024, 0, stream>>>(off1, cur1, bsum1, off2, cur2, bsum2);
    k_scatter2<<<(E1c + E2c + 255) / 256, 256, 0, stream>>>(
        ei1_src, ei1_dst, cur1, perm1, ei2_src, ei2_dst, cur2, perm2);

    // layer 1: aggregate (f32 gather) + pipelined GEMM (64x256 tile: A panels read once)
    k_agg1<<<N1, F_IN / 4, 0, stream>>>(x, perm1, off1, mean1);
    {
        dim3 grid(N1 / 64, F_HID / 256);   // (640, 1)
        k_gemm<1, 4, 4, 4, F_IN, 3, float><<<grid, 256, 0, stream>>>(
            mean1, x, W1lT, W1rT, b1, N1, F_HID, 1, h, nullptr);
    }

    // layer 2: aggregate + pipelined GEMM (64x64 tile, 128 blocks)
    k_agg2<<<N2, F_HID / 4, 0, stream>>>(h, perm2, off2, mean2);
    {
        dim3 grid(N2 / 64, F_OUT / 64);    // (64, 2)
        k_gemm<2, 2, 2, 2, F_HID, 4, ushort><<<grid, 256, 0, stream>>>(
            mean2, h, W2lT, W2rT, b2, N2, F_OUT, 0, nullptr, out);
    }
}